// Round 14
// baseline (282.581 us; speedup 1.0000x reference)
//
#include <hip/hip_runtime.h>
#include <cstdint>
#include <cstddef>

typedef _Float16 v8h __attribute__((ext_vector_type(8)));
typedef _Float16 v4h __attribute__((ext_vector_type(4)));
typedef _Float16 v2h __attribute__((ext_vector_type(2)));
typedef float v4f __attribute__((ext_vector_type(4)));
typedef float v16f __attribute__((ext_vector_type(16)));

#define NH 16
#define HD 128
#define SLEN 2048
#define BATCH 2
#define HID 2048

// async global->LDS, 16B per lane. LDS dest is wave-uniform base + lane*16.
__device__ __forceinline__ void gload16(const void* gptr, void* lptr) {
  __builtin_amdgcn_global_load_lds(
      (const __attribute__((address_space(1))) unsigned int*)gptr,
      (__attribute__((address_space(3))) unsigned int*)lptr, 16, 0, 0);
}

__device__ __forceinline__ uint32_t pkh(float a, float b) {
  return __builtin_bit_cast(uint32_t, __builtin_amdgcn_cvt_pkrtz(a, b));
}
__device__ __forceinline__ v2h pkh2(float a, float b) {
  return __builtin_bit_cast(v2h, __builtin_amdgcn_cvt_pkrtz(a, b));
}
// unambiguous cross-half (lane ^ 32) exchange via ds_bpermute
__device__ __forceinline__ uint32_t xswap32(uint32_t x) {
  return (uint32_t)__shfl_xor((int)x, 32, 64);
}

// ---------------------------------------------------------------------------
// small prep kernels
// ---------------------------------------------------------------------------

__global__ __launch_bounds__(256) void cast_x_kernel(const float* __restrict__ in,
                                                     _Float16* __restrict__ out, int n4) {
  int i = blockIdx.x * 256 + threadIdx.x;
  if (i >= n4) return;
  const float4 v = ((const float4*)in)[i];
  v4h o; o[0] = (_Float16)v.x; o[1] = (_Float16)v.y; o[2] = (_Float16)v.z; o[3] = (_Float16)v.w;
  *(v4h*)(out + (size_t)i * 4) = o;
}

// W [R][C] fp32 -> WT [C][R] f16, 64x64 tiles, vectorized v2h stores
__global__ __launch_bounds__(256) void transpose_cast_kernel(const float* __restrict__ W,
                                                             _Float16* __restrict__ WT,
                                                             int R, int C) {
  __shared__ float tl[64][65];  // [c][r]
  int tx = threadIdx.x, ty = threadIdx.y;  // (32, 8)
  int c0 = blockIdx.x * 64, r0 = blockIdx.y * 64;
#pragma unroll
  for (int i = 0; i < 8; ++i) {
    int r = ty + i * 8;
#pragma unroll
    for (int j = 0; j < 2; ++j) {
      int c = tx + j * 32;
      tl[c][r] = W[(size_t)(r0 + r) * C + c0 + c];
    }
  }
  __syncthreads();
#pragma unroll
  for (int i = 0; i < 8; ++i) {
    int c = ty + i * 8;
    v2h o; o[0] = (_Float16)tl[c][2 * tx]; o[1] = (_Float16)tl[c][2 * tx + 1];
    *(v2h*)(WT + (size_t)(c0 + c) * R + r0 + 2 * tx) = o;
  }
}

// packed {cos, sin} fp32 table: csl[s*64 + d]
__global__ void rope_table_kernel(float2* __restrict__ csl) {
  int s = blockIdx.x, i = threadIdx.x;  // 2048 blocks x 64 threads
  float inv = powf(10000.0f, -(float)i * (1.0f / 64.0f));
  float ang = (float)s * inv;
  csl[s * 64 + i] = make_float2(cosf(ang), sinf(ang));
}

// ---------------------------------------------------------------------------
// 128x128 GEMM, SINGLE-buffered LDS (32 KB -> 5 blocks/CU; m97's actual
// config — stage latency hidden by cross-block TLP, not dbuf).
// MODE 0: QKV epilogue with fused RoPE for q/k tiles (wave-pair exchange via
// freed LDS, f16 bounce) and fused V-transpose for v tiles.
// MODE 1: plain fp32 store.
// ---------------------------------------------------------------------------
template <int MODE>
__global__ __launch_bounds__(256) void gemm_kernel(const _Float16* __restrict__ A,
                                                   const _Float16* __restrict__ BT,
                                                   int M, int N, int K, int gy,
                                                   _Float16* __restrict__ q_out,
                                                   _Float16* __restrict__ k_out,
                                                   _Float16* __restrict__ vt_out,
                                                   float* __restrict__ f_out,
                                                   const float2* __restrict__ csl) {
  __shared__ alignas(16) char LDSBUF[32768];   // A tile 16KB | B tile 16KB
  char* Asb = LDSBUF;
  char* Bsb = LDSBUF + 16384;
  const int t = threadIdx.x;
  const int w = t >> 6;
  const int l = t & 63;
  const int wr = w >> 1, wc = w & 1;

  const int total = gridDim.x;
  const int F = blockIdx.x;
  const int gid = (F & 7) * (total >> 3) + (F >> 3);
  const int bx = gid / gy, by = gid % gy;
  const int m0 = by * 128;
  const int n0 = bx * 128;

  const char* aS[4];
  const char* bS[4];
  {
    const int Kb = K * 2;
#pragma unroll
    for (int j = 0; j < 4; ++j) {
      int c = w * 256 + j * 64 + l;
      int row = c >> 3;
      int col = ((c & 7) * 16) ^ ((row & 7) << 4);
      aS[j] = (const char*)A + (size_t)(m0 + row) * Kb + col;
      bS[j] = (const char*)BT + (size_t)(n0 + row) * Kb + col;
    }
  }

  const v4f vzero = {0.f, 0.f, 0.f, 0.f};
  v4f acc[4][4];
#pragma unroll
  for (int mi = 0; mi < 4; ++mi)
#pragma unroll
    for (int ni = 0; ni < 4; ++ni) acc[mi][ni] = vzero;

  auto stage = [&](int ks) {
#pragma unroll
    for (int j = 0; j < 4; ++j) {
      gload16(aS[j] + ks * 128, Asb + w * 4096 + j * 1024);
      gload16(bS[j] + ks * 128, Bsb + w * 4096 + j * 1024);
    }
  };

  const int nk = K >> 6;
  for (int ks = 0; ks < nk; ++ks) {
    stage(ks);
    asm volatile("s_waitcnt vmcnt(0)" ::: "memory");
    __syncthreads();
#pragma unroll
    for (int kk = 0; kk < 2; ++kk) {
      v8h a[4], b[4];
#pragma unroll
      for (int mi = 0; mi < 4; ++mi) {
        int row = wr * 64 + mi * 16 + (l & 15);
        a[mi] = *(const v8h*)(Asb + row * 128 + ((kk * 64 + ((l >> 4) * 16)) ^ ((row & 7) << 4)));
      }
#pragma unroll
      for (int ni = 0; ni < 4; ++ni) {
        int row = wc * 64 + ni * 16 + (l & 15);
        b[ni] = *(const v8h*)(Bsb + row * 128 + ((kk * 64 + ((l >> 4) * 16)) ^ ((row & 7) << 4)));
      }
      __builtin_amdgcn_s_setprio(1);
#pragma unroll
      for (int mi = 0; mi < 4; ++mi)
#pragma unroll
        for (int ni = 0; ni < 4; ++ni)
          acc[mi][ni] = __builtin_amdgcn_mfma_f32_16x16x32_f16(a[mi], b[ni], acc[mi][ni], 0, 0, 0);
      __builtin_amdgcn_s_setprio(0);
    }
    __syncthreads();  // all reads done before next stage overwrites
  }

  if (MODE == 1) {
#pragma unroll
    for (int mi = 0; mi < 4; ++mi)
#pragma unroll
      for (int ni = 0; ni < 4; ++ni) {
        int n = n0 + wc * 64 + ni * 16 + (l & 15);
#pragma unroll
        for (int r = 0; r < 4; ++r) {
          int m = m0 + wr * 64 + mi * 16 + (l >> 4) * 4 + r;
          f_out[(size_t)m * N + n] = acc[mi][ni][r];
        }
      }
  } else {
    // tile type: bx%3 -> 0=q, 1=k, 2=v; head = bx/3; d = (n - n0)
    const int bt = bx % 3;
    const int head = bx / 3;
    const int l15 = l & 15;
    const int h4 = (l >> 4) * 4;
    if (bt == 2) {
      // ---- fused V-transpose: acc -> LDS [128 d][128 m'] f16 -> VT[bh][d][s]
      _Float16* vb = (_Float16*)LDSBUF;  // full 32 KB scratch (K-loop done)
#pragma unroll
      for (int mi = 0; mi < 4; ++mi)
#pragma unroll
        for (int ni = 0; ni < 4; ++ni) {
          int d = wc * 64 + ni * 16 + l15;
#pragma unroll
          for (int r = 0; r < 4; ++r) {
            int mm = wr * 64 + mi * 16 + h4 + r;
            vb[d * 128 + (mm ^ ((d & 15) << 2))] = (_Float16)acc[mi][ni][r];
          }
        }
      __syncthreads();
      const int s0 = m0 >> 1;
      for (int i = 0; i < 64; ++i) {
        int row = w * 64 + i;          // 0..255 = 128 d x 2 b
        int d = row >> 1, b = row & 1;
        int mm = 2 * l + b;
        _Float16 val = vb[d * 128 + (mm ^ ((d & 15) << 2))];
        vt_out[(((size_t)(b * NH + head)) * HD + d) * SLEN + s0 + l] = val;
      }
    } else {
      _Float16* dst = (bt == 0) ? q_out : k_out;
      // wave-pair RoPE exchange through LDS (f16 bounce, 8KB/wave);
      // partner = w^1 (same wr, flipped wc)
      _Float16* xb2 = (_Float16*)(LDSBUF + (size_t)w * 8192);
      _Float16* pb2 = (_Float16*)(LDSBUF + (size_t)(w ^ 1) * 8192);
#pragma unroll
      for (int mi = 0; mi < 4; ++mi)
#pragma unroll
        for (int ni = 0; ni < 4; ++ni)
#pragma unroll
          for (int r = 0; r < 4; ++r) {
            int row = h4 + r;
            xb2[(mi * 4 + ni) * 256 + row * 16 + (l15 ^ row)] = (_Float16)acc[mi][ni][r];
          }
      __syncthreads();
      const float sgn = (wc == 0) ? -1.f : 1.f;
#pragma unroll
      for (int mi = 0; mi < 4; ++mi) {
#pragma unroll
        for (int ni = 0; ni < 4; ++ni) {
          int dd = ni * 16 + l15;        // d & 63
          int d = wc * 64 + dd;
#pragma unroll
          for (int r = 0; r < 4; ++r) {
            int row = h4 + r;
            int m = m0 + wr * 64 + mi * 16 + row;
            int s = m >> 1;
            float partner = (float)pb2[(mi * 4 + ni) * 256 + row * 16 + (l15 ^ row)];
            const float2 cs = csl[s * 64 + dd];
            float val = acc[mi][ni][r] * cs.x + sgn * partner * cs.y;
            dst[(((size_t)((m & 1) * NH + head)) * SLEN + s) * HD + d] = (_Float16)val;
          }
        }
      }
    }
  }
}

// ---------------------------------------------------------------------------
// Flash attention, 32x32-mfma swapped-QK^T, LDS-staged (round-11 proven).
// ---------------------------------------------------------------------------
__global__ __launch_bounds__(256, 2) void attn_kernel(const _Float16* __restrict__ Qb,
                                                      const _Float16* __restrict__ Kb,
                                                      const _Float16* __restrict__ VTb,
                                                      _Float16* __restrict__ ctx) {
  __shared__ alignas(16) char Ks[2][16384];  // [64 keys][128 d] swizzled rows of 256B
  __shared__ alignas(16) char Vs[2][16384];  // [128 d][64 keys] swizzled rows of 128B
  const int t = threadIdx.x;
  const int w = t >> 6;
  const int l = t & 63;
  const int F = blockIdx.x;                  // [0,512)
  const int bh = (F & 7) + 8 * ((F >> 3) & 3);
  const int prx = F >> 5;                    // 0..15
  const int pr = (F < 256) ? prx : 23 - prx; // bijective per bh; pairs long+short per CU
  const int ta = pr, tb = 31 - pr;
  const int grp = w >> 1;                    // 0 -> tile ta, 1 -> tile tb
  const int tile = grp ? tb : ta;
  const int q0 = tile * 64 + (w & 1) * 32;
  const int l31 = l & 31, g = l >> 5;
  const int q = q0 + l31;                    // this lane's q row

  const _Float16* Qp = Qb + (size_t)bh * SLEN * HD;
  const _Float16* Kp = Kb + (size_t)bh * SLEN * HD;
  const _Float16* Vp = VTb + (size_t)bh * HD * SLEN;

  // per-lane inverse-swizzled staging sources (verbatim round-2 pattern)
  const char* kS[4];
  const char* vS[4];
#pragma unroll
  for (int j = 0; j < 4; ++j) {
    int c = w * 256 + j * 64 + l;
    {
      int row = c >> 4;
      int col = ((c & 15) * 16) ^ ((row & 7) << 4);
      kS[j] = (const char*)Kp + (size_t)row * 256 + col;
    }
    {
      int row = c >> 3;
      int col = ((c & 7) * 16) ^ ((row & 7) << 4);
      vS[j] = (const char*)Vp + (size_t)row * (SLEN * 2) + col;
    }
  }
  auto stage = [&](int kt, int d) {
#pragma unroll
    for (int j = 0; j < 4; ++j) {
      gload16(kS[j] + (size_t)kt * 16384, &Ks[d][w * 4096 + j * 1024]);
      gload16(vS[j] + (size_t)kt * 128, &Vs[d][w * 4096 + j * 1024]);
    }
  };

  // hoist Q: B-frag chunks, chunk c covers d = 16c + 8g + j
  v8h qf[8];
#pragma unroll
  for (int c = 0; c < 8; ++c)
    qf[c] = *(const v8h*)(Qp + (size_t)q * HD + c * 16 + g * 8);

  v16f oT[4];
#pragma unroll
  for (int dc = 0; dc < 4; ++dc)
#pragma unroll
    for (int r = 0; r < 16; ++r) oT[dc][r] = 0.f;
  float m_run = -1e30f, l_run = 0.f;
  const float scale = 0.08838834764831845f;  // 1/sqrt(128)

  stage(0, 0);
  for (int kt = 0; kt <= tb; ++kt) {
    asm volatile("s_waitcnt vmcnt(0)" ::: "memory");
    __syncthreads();
    if (kt < tb) stage(kt + 1, (kt + 1) & 1);
    if (grp == 0 && kt > ta) continue;       // wave-uniform skip
    const char* Kst = Ks[kt & 1];
    const char* Vst = Vs[kt & 1];

    // ---- S^T = K * Q^T : two 32-key halves, 8 d-chunks each ----
    v16f s0, s1;
#pragma unroll
    for (int r = 0; r < 16; ++r) { s0[r] = 0.f; s1[r] = 0.f; }
    __builtin_amdgcn_s_setprio(1);
#pragma unroll
    for (int c = 0; c < 8; ++c) {
      int cofs = (c * 32 + g * 16);
      v8h kf0 = *(const v8h*)(Kst + l31 * 256 + (cofs ^ ((l31 & 7) << 4)));
      v8h kf1 = *(const v8h*)(Kst + (32 + l31) * 256 + (cofs ^ ((l31 & 7) << 4)));
      s0 = __builtin_amdgcn_mfma_f32_32x32x16_f16(kf0, qf[c], s0, 0, 0, 0);
      s1 = __builtin_amdgcn_mfma_f32_32x32x16_f16(kf1, qf[c], s1, 0, 0, 0);
    }
    __builtin_amdgcn_s_setprio(0);

    // ---- scale + causal mask; pv[i] holds key kv0 + 32*(i>>4) + kofs ----
    const bool diag = (kt == tile);
    const int kv0 = kt * 64;
    float pv[32];
#pragma unroll
    for (int r = 0; r < 16; ++r) {
      int kofs = (r & 3) + 8 * (r >> 2) + 4 * g;
      float a = s0[r] * scale;
      float b = s1[r] * scale;
      if (diag) {
        if (kv0 + kofs > q) a = -1e4f;
        if (kv0 + 32 + kofs > q) b = -1e4f;
      }
      pv[r] = a;
      pv[16 + r] = b;
    }

    // ---- row max: in-lane tree + cross-half merge ----
    float mx[8];
#pragma unroll
    for (int i = 0; i < 8; ++i)
      mx[i] = fmaxf(fmaxf(pv[i], pv[i + 8]), fmaxf(pv[i + 16], pv[i + 24]));
    float pm = fmaxf(fmaxf(fmaxf(mx[0], mx[1]), fmaxf(mx[2], mx[3])),
                     fmaxf(fmaxf(mx[4], mx[5]), fmaxf(mx[6], mx[7])));
    float pmall = fmaxf(pm, __shfl_xor(pm, 32, 64));

    // ---- defer-max (T13, THR=8) ----
    float mnew;
    if (__all(pmall - m_run <= 8.f)) {
      mnew = m_run;
    } else {
      mnew = fmaxf(m_run, pmall);
      float alpha = __expf(m_run - mnew);
      m_run = mnew;
      l_run *= alpha;
#pragma unroll
      for (int dc = 0; dc < 4; ++dc)
#pragma unroll
        for (int r = 0; r < 16; ++r) oT[dc][r] *= alpha;
    }

    // ---- exp + row sum ----
    float sacc0 = 0.f, sacc1 = 0.f, sacc2 = 0.f, sacc3 = 0.f;
#pragma unroll
    for (int i = 0; i < 8; ++i) { pv[i] = __expf(pv[i] - mnew); sacc0 += pv[i]; }
#pragma unroll
    for (int i = 8; i < 16; ++i) { pv[i] = __expf(pv[i] - mnew); sacc1 += pv[i]; }
#pragma unroll
    for (int i = 16; i < 24; ++i) { pv[i] = __expf(pv[i] - mnew); sacc2 += pv[i]; }
#pragma unroll
    for (int i = 24; i < 32; ++i) { pv[i] = __expf(pv[i] - mnew); sacc3 += pv[i]; }
    float ssum = (sacc0 + sacc1) + (sacc2 + sacc3);
    l_run += ssum + __shfl_xor(ssum, 32, 64);

    // ---- O^T += VT * P^T : P-frags via cvt_pk + cross-half exchange ----
    __builtin_amdgcn_s_setprio(1);
#pragma unroll
    for (int c = 0; c < 4; ++c) {          // key chunk of 16
      int base = (c >> 1) * 16 + (c & 1) * 8;
      uint32_t P0 = pkh(pv[base + 0], pv[base + 1]);
      uint32_t P1 = pkh(pv[base + 2], pv[base + 3]);
      uint32_t P2 = pkh(pv[base + 4], pv[base + 5]);
      uint32_t P3 = pkh(pv[base + 6], pv[base + 7]);
      uint32_t T0 = g ? P0 : P2;
      uint32_t T1 = g ? P1 : P3;
      uint32_t U0 = xswap32(T0);
      uint32_t U1 = xswap32(T1);
      union { uint32_t u[4]; v8h h; } pu;
      pu.u[0] = g ? U0 : P0;
      pu.u[1] = g ? U1 : P1;
      pu.u[2] = g ? P2 : U0;
      pu.u[3] = g ? P3 : U1;
      v8h pf = pu.h;
      int cofs = c * 32 + g * 16;
#pragma unroll
      for (int dc = 0; dc < 4; ++dc) {
        int vrow = dc * 32 + l31;
        v8h vf = *(const v8h*)(Vst + vrow * 128 + (cofs ^ ((vrow & 7) << 4)));
        oT[dc] = __builtin_amdgcn_mfma_f32_32x32x16_f16(vf, pf, oT[dc], 0, 0, 0);
      }
    }
    __builtin_amdgcn_s_setprio(0);
  }

  // ---- epilogue: O^T col q per lane; divide by l and store ----
  const float inv = 1.0f / l_run;
  const int b = bh >> 4;
  const int hh = bh & 15;
  _Float16* orow = ctx + ((size_t)q * BATCH + b) * HID + hh * HD;
#pragma unroll
  for (int dc = 0; dc < 4; ++dc) {
#pragma unroll
    for (int rr = 0; rr < 4; ++rr) {
      v2h w0 = pkh2(oT[dc][4 * rr + 0] * inv, oT[dc][4 * rr + 1] * inv);
      v2h w1 = pkh2(oT[dc][4 * rr + 2] * inv, oT[dc][4 * rr + 3] * inv);
      v4h o4; o4[0] = w0[0]; o4[1] = w0[1]; o4[2] = w1[0]; o4[3] = w1[1];
      *(v4h*)(orow + dc * 32 + rr * 8 + g * 4) = o4;
    }
  }
}

// ---------------------------------------------------------------------------

extern "C" void kernel_launch(void* const* d_in, const int* in_sizes, int n_in,
                              void* d_out, int out_size, void* d_ws, size_t ws_size,
                              hipStream_t stream) {
  const float* x = (const float*)d_in[0];
  const float* w_qkv = (const float*)d_in[1];
  const float* w_dense = (const float*)d_in[2];
  float* out = (float*)d_out;
  char* ws = (char*)d_ws;

  _Float16* xb    = (_Float16*)(ws);               // 4096x2048        16 MB
  _Float16* wqkvT = (_Float16*)(ws + 16777216);    // 6144x2048        24 MB
  _Float16* wdT   = (_Float16*)(ws + 41943040);    // 2048x2048         8 MB
  _Float16* Qb    = (_Float16*)(ws + 50331648);    // [32][2048][128]  16 MB
  _Float16* Kb    = (_Float16*)(ws + 67108864);    // [32][2048][128]  16 MB
  _Float16* VTb   = (_Float16*)(ws + 100663296);   // [32][128][2048]  16 MB
  _Float16* ctx   = (_Float16*)(ws + 117440512);   // 4096x2048        16 MB
  float2* csl     = (float2*)(ws + 134217728);     // 2048x64 float2    1 MB

  cast_x_kernel<<<dim3(8192), dim3(256), 0, stream>>>(x, xb, 2097152);
  transpose_cast_kernel<<<dim3(96, 32), dim3(32, 8), 0, stream>>>(w_qkv, wqkvT, 2048, 6144);
  transpose_cast_kernel<<<dim3(32, 32), dim3(32, 8), 0, stream>>>(w_dense, wdT, 2048, 2048);
  rope_table_kernel<<<dim3(2048), dim3(64), 0, stream>>>(csl);

  gemm_kernel<0><<<dim3(1536), dim3(256), 0, stream>>>(xb, wqkvT, 4096, 6144, 2048, 32,
                                                       Qb, Kb, VTb, (float*)nullptr, csl);
  attn_kernel<<<dim3(512), dim3(256), 0, stream>>>(Qb, Kb, VTb, ctx);
  gemm_kernel<1><<<dim3(512), dim3(256), 0, stream>>>(ctx, wdT, 4096, 2048, 2048, 32,
                                                      (_Float16*)nullptr, (_Float16*)nullptr,
                                                      (_Float16*)nullptr, out,
                                                      (const float2*)nullptr);
}

// Round 15
// 268.930 us; speedup vs baseline: 1.0508x; 1.0508x over previous
//
#include <hip/hip_runtime.h>
#include <cstdint>
#include <cstddef>

typedef _Float16 v8h __attribute__((ext_vector_type(8)));
typedef _Float16 v4h __attribute__((ext_vector_type(4)));
typedef _Float16 v2h __attribute__((ext_vector_type(2)));
typedef float v4f __attribute__((ext_vector_type(4)));
typedef float v16f __attribute__((ext_vector_type(16)));

#define NH 16
#define HD 128
#define SLEN 2048
#define BATCH 2
#define HID 2048

// async global->LDS, 16B per lane. LDS dest is wave-uniform base + lane*16.
__device__ __forceinline__ void gload16(const void* gptr, void* lptr) {
  __builtin_amdgcn_global_load_lds(
      (const __attribute__((address_space(1))) unsigned int*)gptr,
      (__attribute__((address_space(3))) unsigned int*)lptr, 16, 0, 0);
}

__device__ __forceinline__ uint32_t pkh(float a, float b) {
  return __builtin_bit_cast(uint32_t, __builtin_amdgcn_cvt_pkrtz(a, b));
}
__device__ __forceinline__ v2h pkh2(float a, float b) {
  return __builtin_bit_cast(v2h, __builtin_amdgcn_cvt_pkrtz(a, b));
}
// unambiguous cross-half (lane ^ 32) exchange via ds_bpermute
__device__ __forceinline__ uint32_t xswap32(uint32_t x) {
  return (uint32_t)__shfl_xor((int)x, 32, 64);
}

// ---------------------------------------------------------------------------
// small prep kernels
// ---------------------------------------------------------------------------

__global__ __launch_bounds__(256) void cast_x_kernel(const float* __restrict__ in,
                                                     _Float16* __restrict__ out, int n4) {
  int i = blockIdx.x * 256 + threadIdx.x;
  if (i >= n4) return;
  const float4 v = ((const float4*)in)[i];
  v4h o; o[0] = (_Float16)v.x; o[1] = (_Float16)v.y; o[2] = (_Float16)v.z; o[3] = (_Float16)v.w;
  *(v4h*)(out + (size_t)i * 4) = o;
}

// W [R][C] fp32 -> WT [C][R] f16, 64x64 tiles, vectorized v2h stores
__global__ __launch_bounds__(256) void transpose_cast_kernel(const float* __restrict__ W,
                                                             _Float16* __restrict__ WT,
                                                             int R, int C) {
  __shared__ float tl[64][65];  // [c][r]
  int tx = threadIdx.x, ty = threadIdx.y;  // (32, 8)
  int c0 = blockIdx.x * 64, r0 = blockIdx.y * 64;
#pragma unroll
  for (int i = 0; i < 8; ++i) {
    int r = ty + i * 8;
#pragma unroll
    for (int j = 0; j < 2; ++j) {
      int c = tx + j * 32;
      tl[c][r] = W[(size_t)(r0 + r) * C + c0 + c];
    }
  }
  __syncthreads();
#pragma unroll
  for (int i = 0; i < 8; ++i) {
    int c = ty + i * 8;
    v2h o; o[0] = (_Float16)tl[c][2 * tx]; o[1] = (_Float16)tl[c][2 * tx + 1];
    *(v2h*)(WT + (size_t)(c0 + c) * R + r0 + 2 * tx) = o;
  }
}

// packed {cos, sin} fp32 table: csl[s*64 + d]
__global__ void rope_table_kernel(float2* __restrict__ csl) {
  int s = blockIdx.x, i = threadIdx.x;  // 2048 blocks x 64 threads
  float inv = powf(10000.0f, -(float)i * (1.0f / 64.0f));
  float ang = (float)s * inv;
  csl[s * 64 + i] = make_float2(cosf(ang), sinf(ang));
}

// ---------------------------------------------------------------------------
// 128x128 GEMM (m97-structure, double-buffered — round-13 proven config).
// MODE 0: QKV epilogue with fused RoPE for q/k tiles (wave-pair exchange via
// freed LDS) and fused V-transpose for v tiles (LDS bounce -> VT[bh][d][s]).
// MODE 1: plain fp32 store.
// ---------------------------------------------------------------------------
template <int MODE>
__global__ __launch_bounds__(256) void gemm_kernel(const _Float16* __restrict__ A,
                                                   const _Float16* __restrict__ BT,
                                                   int M, int N, int K, int gy,
                                                   _Float16* __restrict__ q_out,
                                                   _Float16* __restrict__ k_out,
                                                   _Float16* __restrict__ vt_out,
                                                   float* __restrict__ f_out,
                                                   const float2* __restrict__ csl) {
  __shared__ alignas(16) char As[2][16384];
  __shared__ alignas(16) char Bs[2][16384];
  const int t = threadIdx.x;
  const int w = t >> 6;
  const int l = t & 63;
  const int wr = w >> 1, wc = w & 1;

  const int total = gridDim.x;
  const int F = blockIdx.x;
  const int gid = (F & 7) * (total >> 3) + (F >> 3);
  const int bx = gid / gy, by = gid % gy;
  const int m0 = by * 128;
  const int n0 = bx * 128;

  const char* aS[4];
  const char* bS[4];
  {
    const int Kb = K * 2;
#pragma unroll
    for (int j = 0; j < 4; ++j) {
      int c = w * 256 + j * 64 + l;
      int row = c >> 3;
      int col = ((c & 7) * 16) ^ ((row & 7) << 4);
      aS[j] = (const char*)A + (size_t)(m0 + row) * Kb + col;
      bS[j] = (const char*)BT + (size_t)(n0 + row) * Kb + col;
    }
  }

  const v4f vzero = {0.f, 0.f, 0.f, 0.f};
  v4f acc[4][4];
#pragma unroll
  for (int mi = 0; mi < 4; ++mi)
#pragma unroll
    for (int ni = 0; ni < 4; ++ni) acc[mi][ni] = vzero;

  auto stage = [&](int ks, int d) {
#pragma unroll
    for (int j = 0; j < 4; ++j) {
      gload16(aS[j] + ks * 128, &As[d][w * 4096 + j * 1024]);
      gload16(bS[j] + ks * 128, &Bs[d][w * 4096 + j * 1024]);
    }
  };

  const int nk = K >> 6;
  stage(0, 0);
  for (int ks = 0; ks < nk; ++ks) {
    asm volatile("s_waitcnt vmcnt(0)" ::: "memory");
    __syncthreads();
    if (ks + 1 < nk) stage(ks + 1, (ks + 1) & 1);
    const char* Ap = As[ks & 1];
    const char* Bp = Bs[ks & 1];
#pragma unroll
    for (int kk = 0; kk < 2; ++kk) {
      v8h a[4], b[4];
#pragma unroll
      for (int mi = 0; mi < 4; ++mi) {
        int row = wr * 64 + mi * 16 + (l & 15);
        a[mi] = *(const v8h*)(Ap + row * 128 + ((kk * 64 + ((l >> 4) * 16)) ^ ((row & 7) << 4)));
      }
#pragma unroll
      for (int ni = 0; ni < 4; ++ni) {
        int row = wc * 64 + ni * 16 + (l & 15);
        b[ni] = *(const v8h*)(Bp + row * 128 + ((kk * 64 + ((l >> 4) * 16)) ^ ((row & 7) << 4)));
      }
      __builtin_amdgcn_s_setprio(1);
#pragma unroll
      for (int mi = 0; mi < 4; ++mi)
#pragma unroll
        for (int ni = 0; ni < 4; ++ni)
          acc[mi][ni] = __builtin_amdgcn_mfma_f32_16x16x32_f16(a[mi], b[ni], acc[mi][ni], 0, 0, 0);
      __builtin_amdgcn_s_setprio(0);
    }
  }

  if (MODE == 1) {
#pragma unroll
    for (int mi = 0; mi < 4; ++mi)
#pragma unroll
      for (int ni = 0; ni < 4; ++ni) {
        int n = n0 + wc * 64 + ni * 16 + (l & 15);
#pragma unroll
        for (int r = 0; r < 4; ++r) {
          int m = m0 + wr * 64 + mi * 16 + (l >> 4) * 4 + r;
          f_out[(size_t)m * N + n] = acc[mi][ni][r];
        }
      }
  } else {
    // tile type: bx%3 -> 0=q, 1=k, 2=v; head = bx/3; d = (n - n0)
    const int bt = bx % 3;
    const int head = bx / 3;
    const int l15 = l & 15;
    const int h4 = (l >> 4) * 4;
    if (bt == 2) {
      // ---- fused V-transpose: acc -> LDS [128 d][128 m'] f16 -> VT[bh][d][s]
      _Float16* vb = (_Float16*)&As[0][0];  // 32 KB scratch (K-loop done)
      __syncthreads();  // all K-loop LDS reads complete before overwrite
#pragma unroll
      for (int mi = 0; mi < 4; ++mi)
#pragma unroll
        for (int ni = 0; ni < 4; ++ni) {
          int d = wc * 64 + ni * 16 + l15;
#pragma unroll
          for (int r = 0; r < 4; ++r) {
            int mm = wr * 64 + mi * 16 + h4 + r;
            vb[d * 128 + (mm ^ ((d & 15) << 2))] = (_Float16)acc[mi][ni][r];
          }
        }
      __syncthreads();
      const int s0 = m0 >> 1;
      for (int i = 0; i < 64; ++i) {
        int row = w * 64 + i;          // 0..255 = 128 d x 2 b
        int d = row >> 1, b = row & 1;
        int mm = 2 * l + b;
        _Float16 val = vb[d * 128 + (mm ^ ((d & 15) << 2))];
        vt_out[(((size_t)(b * NH + head)) * HD + d) * SLEN + s0 + l] = val;
      }
    } else {
      _Float16* dst = (bt == 0) ? q_out : k_out;
      // wave-pair RoPE exchange: wave w slice = 16KB; partner = w^1 (wc flip)
      float* xb2 = (w < 2) ? (float*)As + (size_t)w * 4096
                           : (float*)Bs + (size_t)(w - 2) * 4096;
      float* pb2 = ((w ^ 1) < 2) ? (float*)As + (size_t)(w ^ 1) * 4096
                                 : (float*)Bs + (size_t)((w ^ 1) - 2) * 4096;
      __syncthreads();  // K-loop LDS reads complete before overwrite
#pragma unroll
      for (int mi = 0; mi < 4; ++mi)
#pragma unroll
        for (int ni = 0; ni < 4; ++ni)
#pragma unroll
          for (int r = 0; r < 4; ++r) {
            int row = h4 + r;
            xb2[(mi * 4 + ni) * 256 + row * 16 + (l15 ^ row)] = acc[mi][ni][r];
          }
      __syncthreads();
      const float sgn = (wc == 0) ? -1.f : 1.f;
#pragma unroll
      for (int mi = 0; mi < 4; ++mi) {
#pragma unroll
        for (int ni = 0; ni < 4; ++ni) {
          int dd = ni * 16 + l15;        // d & 63
          int d = wc * 64 + dd;
#pragma unroll
          for (int r = 0; r < 4; ++r) {
            int row = h4 + r;
            int m = m0 + wr * 64 + mi * 16 + row;
            int s = m >> 1;
            float partner = pb2[(mi * 4 + ni) * 256 + row * 16 + (l15 ^ row)];
            const float2 cs = csl[s * 64 + dd];
            float val = acc[mi][ni][r] * cs.x + sgn * partner * cs.y;
            dst[(((size_t)((m & 1) * NH + head)) * SLEN + s) * HD + d] = (_Float16)val;
          }
        }
      }
    }
  }
}

// ---------------------------------------------------------------------------
// Flash attention, 32x32-mfma swapped-QK^T, LDS-staged (round-11 proven).
// Pair remap: pr = (F<256) ? F>>5 : 23-(F>>5) (bijective per bh).
// ---------------------------------------------------------------------------
__global__ __launch_bounds__(256, 2) void attn_kernel(const _Float16* __restrict__ Qb,
                                                      const _Float16* __restrict__ Kb,
                                                      const _Float16* __restrict__ VTb,
                                                      _Float16* __restrict__ ctx) {
  __shared__ alignas(16) char Ks[2][16384];  // [64 keys][128 d] swizzled rows of 256B
  __shared__ alignas(16) char Vs[2][16384];  // [128 d][64 keys] swizzled rows of 128B
  const int t = threadIdx.x;
  const int w = t >> 6;
  const int l = t & 63;
  const int F = blockIdx.x;                  // [0,512)
  const int bh = (F & 7) + 8 * ((F >> 3) & 3);
  const int prx = F >> 5;                    // 0..15
  const int pr = (F < 256) ? prx : 23 - prx; // bijective per bh; pairs long+short per CU
  const int ta = pr, tb = 31 - pr;
  const int grp = w >> 1;                    // 0 -> tile ta, 1 -> tile tb
  const int tile = grp ? tb : ta;
  const int q0 = tile * 64 + (w & 1) * 32;
  const int l31 = l & 31, g = l >> 5;
  const int q = q0 + l31;                    // this lane's q row

  const _Float16* Qp = Qb + (size_t)bh * SLEN * HD;
  const _Float16* Kp = Kb + (size_t)bh * SLEN * HD;
  const _Float16* Vp = VTb + (size_t)bh * HD * SLEN;

  // per-lane inverse-swizzled staging sources (verbatim round-2 pattern)
  const char* kS[4];
  const char* vS[4];
#pragma unroll
  for (int j = 0; j < 4; ++j) {
    int c = w * 256 + j * 64 + l;
    {
      int row = c >> 4;
      int col = ((c & 15) * 16) ^ ((row & 7) << 4);
      kS[j] = (const char*)Kp + (size_t)row * 256 + col;
    }
    {
      int row = c >> 3;
      int col = ((c & 7) * 16) ^ ((row & 7) << 4);
      vS[j] = (const char*)Vp + (size_t)row * (SLEN * 2) + col;
    }
  }
  auto stage = [&](int kt, int d) {
#pragma unroll
    for (int j = 0; j < 4; ++j) {
      gload16(kS[j] + (size_t)kt * 16384, &Ks[d][w * 4096 + j * 1024]);
      gload16(vS[j] + (size_t)kt * 128, &Vs[d][w * 4096 + j * 1024]);
    }
  };

  // hoist Q: B-frag chunks, chunk c covers d = 16c + 8g + j
  v8h qf[8];
#pragma unroll
  for (int c = 0; c < 8; ++c)
    qf[c] = *(const v8h*)(Qp + (size_t)q * HD + c * 16 + g * 8);

  v16f oT[4];
#pragma unroll
  for (int dc = 0; dc < 4; ++dc)
#pragma unroll
    for (int r = 0; r < 16; ++r) oT[dc][r] = 0.f;
  float m_run = -1e30f, l_run = 0.f;
  const float scale = 0.08838834764831845f;  // 1/sqrt(128)

  stage(0, 0);
  for (int kt = 0; kt <= tb; ++kt) {
    asm volatile("s_waitcnt vmcnt(0)" ::: "memory");
    __syncthreads();
    if (kt < tb) stage(kt + 1, (kt + 1) & 1);
    if (grp == 0 && kt > ta) continue;       // wave-uniform skip
    const char* Kst = Ks[kt & 1];
    const char* Vst = Vs[kt & 1];

    // ---- S^T = K * Q^T : two 32-key halves, 8 d-chunks each ----
    v16f s0, s1;
#pragma unroll
    for (int r = 0; r < 16; ++r) { s0[r] = 0.f; s1[r] = 0.f; }
    __builtin_amdgcn_s_setprio(1);
#pragma unroll
    for (int c = 0; c < 8; ++c) {
      int cofs = (c * 32 + g * 16);
      v8h kf0 = *(const v8h*)(Kst + l31 * 256 + (cofs ^ ((l31 & 7) << 4)));
      v8h kf1 = *(const v8h*)(Kst + (32 + l31) * 256 + (cofs ^ ((l31 & 7) << 4)));
      s0 = __builtin_amdgcn_mfma_f32_32x32x16_f16(kf0, qf[c], s0, 0, 0, 0);
      s1 = __builtin_amdgcn_mfma_f32_32x32x16_f16(kf1, qf[c], s1, 0, 0, 0);
    }
    __builtin_amdgcn_s_setprio(0);

    // ---- scale + causal mask; pv[i] holds key kv0 + 32*(i>>4) + kofs ----
    const bool diag = (kt == tile);
    const int kv0 = kt * 64;
    float pv[32];
#pragma unroll
    for (int r = 0; r < 16; ++r) {
      int kofs = (r & 3) + 8 * (r >> 2) + 4 * g;
      float a = s0[r] * scale;
      float b = s1[r] * scale;
      if (diag) {
        if (kv0 + kofs > q) a = -1e4f;
        if (kv0 + 32 + kofs > q) b = -1e4f;
      }
      pv[r] = a;
      pv[16 + r] = b;
    }

    // ---- row max: in-lane tree + cross-half merge ----
    float mx[8];
#pragma unroll
    for (int i = 0; i < 8; ++i)
      mx[i] = fmaxf(fmaxf(pv[i], pv[i + 8]), fmaxf(pv[i + 16], pv[i + 24]));
    float pm = fmaxf(fmaxf(fmaxf(mx[0], mx[1]), fmaxf(mx[2], mx[3])),
                     fmaxf(fmaxf(mx[4], mx[5]), fmaxf(mx[6], mx[7])));
    float pmall = fmaxf(pm, __shfl_xor(pm, 32, 64));

    // ---- defer-max (T13, THR=8) ----
    float mnew;
    if (__all(pmall - m_run <= 8.f)) {
      mnew = m_run;
    } else {
      mnew = fmaxf(m_run, pmall);
      float alpha = __expf(m_run - mnew);
      m_run = mnew;
      l_run *= alpha;
#pragma unroll
      for (int dc = 0; dc < 4; ++dc)
#pragma unroll
        for (int r = 0; r < 16; ++r) oT[dc][r] *= alpha;
    }

    // ---- exp + row sum ----
    float sacc0 = 0.f, sacc1 = 0.f, sacc2 = 0.f, sacc3 = 0.f;
#pragma unroll
    for (int i = 0; i < 8; ++i) { pv[i] = __expf(pv[i] - mnew); sacc0 += pv[i]; }
#pragma unroll
    for (int i = 8; i < 16; ++i) { pv[i] = __expf(pv[i] - mnew); sacc1 += pv[i]; }
#pragma unroll
    for (int i = 16; i < 24; ++i) { pv[i] = __expf(pv[i] - mnew); sacc2 += pv[i]; }
#pragma unroll
    for (int i = 24; i < 32; ++i) { pv[i] = __expf(pv[i] - mnew); sacc3 += pv[i]; }
    float ssum = (sacc0 + sacc1) + (sacc2 + sacc3);
    l_run += ssum + __shfl_xor(ssum, 32, 64);

    // ---- O^T += VT * P^T : P-frags via cvt_pk + cross-half exchange ----
    __builtin_amdgcn_s_setprio(1);
#pragma unroll
    for (int c = 0; c < 4; ++c) {          // key chunk of 16
      int base = (c >> 1) * 16 + (c & 1) * 8;
      uint32_t P0 = pkh(pv[base + 0], pv[base + 1]);
      uint32_t P1 = pkh(pv[base + 2], pv[base + 3]);
      uint32_t P2 = pkh(pv[base + 4], pv[base + 5]);
      uint32_t P3 = pkh(pv[base + 6], pv[base + 7]);
      uint32_t T0 = g ? P0 : P2;
      uint32_t T1 = g ? P1 : P3;
      uint32_t U0 = xswap32(T0);
      uint32_t U1 = xswap32(T1);
      union { uint32_t u[4]; v8h h; } pu;
      pu.u[0] = g ? U0 : P0;
      pu.u[1] = g ? U1 : P1;
      pu.u[2] = g ? P2 : U0;
      pu.u[3] = g ? P3 : U1;
      v8h pf = pu.h;
      int cofs = c * 32 + g * 16;
#pragma unroll
      for (int dc = 0; dc < 4; ++dc) {
        int vrow = dc * 32 + l31;
        v8h vf = *(const v8h*)(Vst + vrow * 128 + (cofs ^ ((vrow & 7) << 4)));
        oT[dc] = __builtin_amdgcn_mfma_f32_32x32x16_f16(vf, pf, oT[dc], 0, 0, 0);
      }
    }
    __builtin_amdgcn_s_setprio(0);
  }

  // ---- epilogue: O^T col q per lane; divide by l and store ----
  const float inv = 1.0f / l_run;
  const int b = bh >> 4;
  const int hh = bh & 15;
  _Float16* orow = ctx + ((size_t)q * BATCH + b) * HID + hh * HD;
#pragma unroll
  for (int dc = 0; dc < 4; ++dc) {
#pragma unroll
    for (int rr = 0; rr < 4; ++rr) {
      v2h w0 = pkh2(oT[dc][4 * rr + 0] * inv, oT[dc][4 * rr + 1] * inv);
      v2h w1 = pkh2(oT[dc][4 * rr + 2] * inv, oT[dc][4 * rr + 3] * inv);
      v4h o4; o4[0] = w0[0]; o4[1] = w0[1]; o4[2] = w1[0]; o4[3] = w1[1];
      *(v4h*)(orow + dc * 32 + rr * 8 + g * 4) = o4;
    }
  }
}

// ---------------------------------------------------------------------------

extern "C" void kernel_launch(void* const* d_in, const int* in_sizes, int n_in,
                              void* d_out, int out_size, void* d_ws, size_t ws_size,
                              hipStream_t stream) {
  const float* x = (const float*)d_in[0];
  const float* w_qkv = (const float*)d_in[1];
  const float* w_dense = (const float*)d_in[2];
  float* out = (float*)d_out;
  char* ws = (char*)d_ws;

  _Float16* xb    = (_Float16*)(ws);               // 4096x2048        16 MB
  _Float16* wqkvT = (_Float16*)(ws + 16777216);    // 6144x2048        24 MB
  _Float16* wdT   = (_Float16*)(ws + 41943040);    // 2048x2048         8 MB
  _Float16* Qb    = (_Float16*)(ws + 50331648);    // [32][2048][128]  16 MB
  _Float16* Kb    = (_Float16*)(ws + 67108864);    // [32][2048][128]  16 MB
  _Float16* VTb   = (_Float16*)(ws + 100663296);   // [32][128][2048]  16 MB
  _Float16* ctx   = (_Float16*)(ws + 117440512);   // 4096x2048        16 MB
  float2* csl     = (float2*)(ws + 134217728);     // 2048x64 float2    1 MB

  cast_x_kernel<<<dim3(8192), dim3(256), 0, stream>>>(x, xb, 2097152);
  transpose_cast_kernel<<<dim3(96, 32), dim3(32, 8), 0, stream>>>(w_qkv, wqkvT, 2048, 6144);
  transpose_cast_kernel<<<dim3(32, 32), dim3(32, 8), 0, stream>>>(w_dense, wdT, 2048, 2048);
  rope_table_kernel<<<dim3(2048), dim3(64), 0, stream>>>(csl);

  gemm_kernel<0><<<dim3(1536), dim3(256), 0, stream>>>(xb, wqkvT, 4096, 6144, 2048, 32,
                                                       Qb, Kb, VTb, (float*)nullptr, csl);
  attn_kernel<<<dim3(512), dim3(256), 0, stream>>>(Qb, Kb, VTb, ctx);
  gemm_kernel<1><<<dim3(512), dim3(256), 0, stream>>>(ctx, wdT, 4096, 2048, 2048, 32,
                                                      (_Float16*)nullptr, (_Float16*)nullptr,
                                                      (_Float16*)nullptr, out,
                                                      (const float2*)nullptr);
}

// Round 16
// 267.687 us; speedup vs baseline: 1.0556x; 1.0046x over previous
//
#include <hip/hip_runtime.h>
#include <cstdint>
#include <cstddef>

typedef _Float16 v8h __attribute__((ext_vector_type(8)));
typedef _Float16 v4h __attribute__((ext_vector_type(4)));
typedef _Float16 v2h __attribute__((ext_vector_type(2)));
typedef float v4f __attribute__((ext_vector_type(4)));
typedef float v16f __attribute__((ext_vector_type(16)));

#define NH 16
#define HD 128
#define SLEN 2048
#define BATCH 2
#define HID 2048

// async global->LDS, 16B per lane. LDS dest is wave-uniform base + lane*16.
__device__ __forceinline__ void gload16(const void* gptr, void* lptr) {
  __builtin_amdgcn_global_load_lds(
      (const __attribute__((address_space(1))) unsigned int*)gptr,
      (__attribute__((address_space(3))) unsigned int*)lptr, 16, 0, 0);
}

__device__ __forceinline__ uint32_t pkh(float a, float b) {
  return __builtin_bit_cast(uint32_t, __builtin_amdgcn_cvt_pkrtz(a, b));
}
__device__ __forceinline__ v2h pkh2(float a, float b) {
  return __builtin_bit_cast(v2h, __builtin_amdgcn_cvt_pkrtz(a, b));
}
// unambiguous cross-half (lane ^ 32) exchange via ds_bpermute
__device__ __forceinline__ uint32_t xswap32(uint32_t x) {
  return (uint32_t)__shfl_xor((int)x, 32, 64);
}

// ---------------------------------------------------------------------------
// small prep kernels
// ---------------------------------------------------------------------------

__global__ __launch_bounds__(256) void cast_x_kernel(const float* __restrict__ in,
                                                     _Float16* __restrict__ out, int n4) {
  int i = blockIdx.x * 256 + threadIdx.x;
  if (i >= n4) return;
  const float4 v = ((const float4*)in)[i];
  v4h o; o[0] = (_Float16)v.x; o[1] = (_Float16)v.y; o[2] = (_Float16)v.z; o[3] = (_Float16)v.w;
  *(v4h*)(out + (size_t)i * 4) = o;
}

// W [R][C] fp32 -> WT [C][R] f16, 64x64 tiles, vectorized v2h stores
__global__ __launch_bounds__(256) void transpose_cast_kernel(const float* __restrict__ W,
                                                             _Float16* __restrict__ WT,
                                                             int R, int C) {
  __shared__ float tl[64][65];  // [c][r]
  int tx = threadIdx.x, ty = threadIdx.y;  // (32, 8)
  int c0 = blockIdx.x * 64, r0 = blockIdx.y * 64;
#pragma unroll
  for (int i = 0; i < 8; ++i) {
    int r = ty + i * 8;
#pragma unroll
    for (int j = 0; j < 2; ++j) {
      int c = tx + j * 32;
      tl[c][r] = W[(size_t)(r0 + r) * C + c0 + c];
    }
  }
  __syncthreads();
#pragma unroll
  for (int i = 0; i < 8; ++i) {
    int c = ty + i * 8;
    v2h o; o[0] = (_Float16)tl[c][2 * tx]; o[1] = (_Float16)tl[c][2 * tx + 1];
    *(v2h*)(WT + (size_t)(c0 + c) * R + r0 + 2 * tx) = o;
  }
}

// packed {cos, sin} fp32 table: csl[s*64 + d]
__global__ void rope_table_kernel(float2* __restrict__ csl) {
  int s = blockIdx.x, i = threadIdx.x;  // 2048 blocks x 64 threads
  float inv = powf(10000.0f, -(float)i * (1.0f / 64.0f));
  float ang = (float)s * inv;
  csl[s * 64 + i] = make_float2(cosf(ang), sinf(ang));
}

// ---------------------------------------------------------------------------
// 128x128 GEMM (m97-structure, double-buffered — round-13 proven config).
// L2 supertile decode: each XCD chunk walks (by-pair x all its bx), keeping
// its B-tiles (<=3MB) + 2 A-rows (1MB) L2-resident -> stage loads mostly
// L2-hits, shortening the per-K-step vmcnt drain.
// MODE 0: QKV epilogue with fused RoPE for q/k tiles (wave-pair exchange via
// freed LDS) and fused V-transpose for v tiles (LDS bounce -> VT[bh][d][s]).
// MODE 1: plain fp32 store.
// ---------------------------------------------------------------------------
template <int MODE>
__global__ __launch_bounds__(256) void gemm_kernel(const _Float16* __restrict__ A,
                                                   const _Float16* __restrict__ BT,
                                                   int M, int N, int K, int gy,
                                                   _Float16* __restrict__ q_out,
                                                   _Float16* __restrict__ k_out,
                                                   _Float16* __restrict__ vt_out,
                                                   float* __restrict__ f_out,
                                                   const float2* __restrict__ csl) {
  __shared__ alignas(16) char As[2][16384];
  __shared__ alignas(16) char Bs[2][16384];
  const int t = threadIdx.x;
  const int w = t >> 6;
  const int l = t & 63;
  const int wr = w >> 1, wc = w & 1;

  const int total = gridDim.x;
  const int F = blockIdx.x;
  // L2 supertile decode (bijective): XCD c gets bx in [c*nbx,(c+1)*nbx);
  // within chunk: by-pairs outer, bx inner -> B-tiles persist in L2.
  const int c = F & 7;
  const int r0_ = F >> 3;                  // [0, total/8)
  const int nbx = total / (8 * gy);        // bx tiles per XCD chunk
  const int sw = 2 * nbx;
  const int g_ = r0_ / sw, s_ = r0_ % sw;
  const int bx = c * nbx + (s_ >> 1);
  const int by = g_ * 2 + (s_ & 1);
  const int m0 = by * 128;
  const int n0 = bx * 128;

  const char* aS[4];
  const char* bS[4];
  {
    const int Kb = K * 2;
#pragma unroll
    for (int j = 0; j < 4; ++j) {
      int cc = w * 256 + j * 64 + l;
      int row = cc >> 3;
      int col = ((cc & 7) * 16) ^ ((row & 7) << 4);
      aS[j] = (const char*)A + (size_t)(m0 + row) * Kb + col;
      bS[j] = (const char*)BT + (size_t)(n0 + row) * Kb + col;
    }
  }

  const v4f vzero = {0.f, 0.f, 0.f, 0.f};
  v4f acc[4][4];
#pragma unroll
  for (int mi = 0; mi < 4; ++mi)
#pragma unroll
    for (int ni = 0; ni < 4; ++ni) acc[mi][ni] = vzero;

  auto stage = [&](int ks, int d) {
#pragma unroll
    for (int j = 0; j < 4; ++j) {
      gload16(aS[j] + ks * 128, &As[d][w * 4096 + j * 1024]);
      gload16(bS[j] + ks * 128, &Bs[d][w * 4096 + j * 1024]);
    }
  };

  const int nk = K >> 6;
  stage(0, 0);
  for (int ks = 0; ks < nk; ++ks) {
    asm volatile("s_waitcnt vmcnt(0)" ::: "memory");
    __syncthreads();
    if (ks + 1 < nk) stage(ks + 1, (ks + 1) & 1);
    const char* Ap = As[ks & 1];
    const char* Bp = Bs[ks & 1];
#pragma unroll
    for (int kk = 0; kk < 2; ++kk) {
      v8h a[4], b[4];
#pragma unroll
      for (int mi = 0; mi < 4; ++mi) {
        int row = wr * 64 + mi * 16 + (l & 15);
        a[mi] = *(const v8h*)(Ap + row * 128 + ((kk * 64 + ((l >> 4) * 16)) ^ ((row & 7) << 4)));
      }
#pragma unroll
      for (int ni = 0; ni < 4; ++ni) {
        int row = wc * 64 + ni * 16 + (l & 15);
        b[ni] = *(const v8h*)(Bp + row * 128 + ((kk * 64 + ((l >> 4) * 16)) ^ ((row & 7) << 4)));
      }
      __builtin_amdgcn_s_setprio(1);
#pragma unroll
      for (int mi = 0; mi < 4; ++mi)
#pragma unroll
        for (int ni = 0; ni < 4; ++ni)
          acc[mi][ni] = __builtin_amdgcn_mfma_f32_16x16x32_f16(a[mi], b[ni], acc[mi][ni], 0, 0, 0);
      __builtin_amdgcn_s_setprio(0);
    }
  }

  if (MODE == 1) {
#pragma unroll
    for (int mi = 0; mi < 4; ++mi)
#pragma unroll
      for (int ni = 0; ni < 4; ++ni) {
        int n = n0 + wc * 64 + ni * 16 + (l & 15);
#pragma unroll
        for (int r = 0; r < 4; ++r) {
          int m = m0 + wr * 64 + mi * 16 + (l >> 4) * 4 + r;
          f_out[(size_t)m * N + n] = acc[mi][ni][r];
        }
      }
  } else {
    // tile type: bx%3 -> 0=q, 1=k, 2=v; head = bx/3; d = (n - n0)
    const int bt = bx % 3;
    const int head = bx / 3;
    const int l15 = l & 15;
    const int h4 = (l >> 4) * 4;
    if (bt == 2) {
      // ---- fused V-transpose: acc -> LDS [128 d][128 m'] f16 -> VT[bh][d][s]
      _Float16* vb = (_Float16*)&As[0][0];  // 32 KB scratch (K-loop done)
      __syncthreads();  // all K-loop LDS reads complete before overwrite
#pragma unroll
      for (int mi = 0; mi < 4; ++mi)
#pragma unroll
        for (int ni = 0; ni < 4; ++ni) {
          int d = wc * 64 + ni * 16 + l15;
#pragma unroll
          for (int r = 0; r < 4; ++r) {
            int mm = wr * 64 + mi * 16 + h4 + r;
            vb[d * 128 + (mm ^ ((d & 15) << 2))] = (_Float16)acc[mi][ni][r];
          }
        }
      __syncthreads();
      const int s0 = m0 >> 1;
      for (int i = 0; i < 64; ++i) {
        int row = w * 64 + i;          // 0..255 = 128 d x 2 b
        int d = row >> 1, b = row & 1;
        int mm = 2 * l + b;
        _Float16 val = vb[d * 128 + (mm ^ ((d & 15) << 2))];
        vt_out[(((size_t)(b * NH + head)) * HD + d) * SLEN + s0 + l] = val;
      }
    } else {
      _Float16* dst = (bt == 0) ? q_out : k_out;
      // wave-pair RoPE exchange: wave w slice = 16KB; partner = w^1 (wc flip)
      float* xb2 = (w < 2) ? (float*)As + (size_t)w * 4096
                           : (float*)Bs + (size_t)(w - 2) * 4096;
      float* pb2 = ((w ^ 1) < 2) ? (float*)As + (size_t)(w ^ 1) * 4096
                                 : (float*)Bs + (size_t)((w ^ 1) - 2) * 4096;
      __syncthreads();  // K-loop LDS reads complete before overwrite
#pragma unroll
      for (int mi = 0; mi < 4; ++mi)
#pragma unroll
        for (int ni = 0; ni < 4; ++ni)
#pragma unroll
          for (int r = 0; r < 4; ++r) {
            int row = h4 + r;
            xb2[(mi * 4 + ni) * 256 + row * 16 + (l15 ^ row)] = acc[mi][ni][r];
          }
      __syncthreads();
      const float sgn = (wc == 0) ? -1.f : 1.f;
#pragma unroll
      for (int mi = 0; mi < 4; ++mi) {
#pragma unroll
        for (int ni = 0; ni < 4; ++ni) {
          int dd = ni * 16 + l15;        // d & 63
          int d = wc * 64 + dd;
#pragma unroll
          for (int r = 0; r < 4; ++r) {
            int row = h4 + r;
            int m = m0 + wr * 64 + mi * 16 + row;
            int s = m >> 1;
            float partner = pb2[(mi * 4 + ni) * 256 + row * 16 + (l15 ^ row)];
            const float2 cs = csl[s * 64 + dd];
            float val = acc[mi][ni][r] * cs.x + sgn * partner * cs.y;
            dst[(((size_t)((m & 1) * NH + head)) * SLEN + s) * HD + d] = (_Float16)val;
          }
        }
      }
    }
  }
}

// ---------------------------------------------------------------------------
// Flash attention, 32x32-mfma swapped-QK^T, LDS-staged (round-11 proven).
// Pair remap: pr = (F<256) ? F>>5 : 23-(F>>5) (bijective per bh).
// ---------------------------------------------------------------------------
__global__ __launch_bounds__(256, 2) void attn_kernel(const _Float16* __restrict__ Qb,
                                                      const _Float16* __restrict__ Kb,
                                                      const _Float16* __restrict__ VTb,
                                                      _Float16* __restrict__ ctx) {
  __shared__ alignas(16) char Ks[2][16384];  // [64 keys][128 d] swizzled rows of 256B
  __shared__ alignas(16) char Vs[2][16384];  // [128 d][64 keys] swizzled rows of 128B
  const int t = threadIdx.x;
  const int w = t >> 6;
  const int l = t & 63;
  const int F = blockIdx.x;                  // [0,512)
  const int bh = (F & 7) + 8 * ((F >> 3) & 3);
  const int prx = F >> 5;                    // 0..15
  const int pr = (F < 256) ? prx : 23 - prx; // bijective per bh; pairs long+short per CU
  const int ta = pr, tb = 31 - pr;
  const int grp = w >> 1;                    // 0 -> tile ta, 1 -> tile tb
  const int tile = grp ? tb : ta;
  const int q0 = tile * 64 + (w & 1) * 32;
  const int l31 = l & 31, g = l >> 5;
  const int q = q0 + l31;                    // this lane's q row

  const _Float16* Qp = Qb + (size_t)bh * SLEN * HD;
  const _Float16* Kp = Kb + (size_t)bh * SLEN * HD;
  const _Float16* Vp = VTb + (size_t)bh * HD * SLEN;

  // per-lane inverse-swizzled staging sources (verbatim round-2 pattern)
  const char* kS[4];
  const char* vS[4];
#pragma unroll
  for (int j = 0; j < 4; ++j) {
    int c = w * 256 + j * 64 + l;
    {
      int row = c >> 4;
      int col = ((c & 15) * 16) ^ ((row & 7) << 4);
      kS[j] = (const char*)Kp + (size_t)row * 256 + col;
    }
    {
      int row = c >> 3;
      int col = ((c & 7) * 16) ^ ((row & 7) << 4);
      vS[j] = (const char*)Vp + (size_t)row * (SLEN * 2) + col;
    }
  }
  auto stage = [&](int kt, int d) {
#pragma unroll
    for (int j = 0; j < 4; ++j) {
      gload16(kS[j] + (size_t)kt * 16384, &Ks[d][w * 4096 + j * 1024]);
      gload16(vS[j] + (size_t)kt * 128, &Vs[d][w * 4096 + j * 1024]);
    }
  };

  // hoist Q: B-frag chunks, chunk c covers d = 16c + 8g + j
  v8h qf[8];
#pragma unroll
  for (int c = 0; c < 8; ++c)
    qf[c] = *(const v8h*)(Qp + (size_t)q * HD + c * 16 + g * 8);

  v16f oT[4];
#pragma unroll
  for (int dc = 0; dc < 4; ++dc)
#pragma unroll
    for (int r = 0; r < 16; ++r) oT[dc][r] = 0.f;
  float m_run = -1e30f, l_run = 0.f;
  const float scale = 0.08838834764831845f;  // 1/sqrt(128)

  stage(0, 0);
  for (int kt = 0; kt <= tb; ++kt) {
    asm volatile("s_waitcnt vmcnt(0)" ::: "memory");
    __syncthreads();
    if (kt < tb) stage(kt + 1, (kt + 1) & 1);
    if (grp == 0 && kt > ta) continue;       // wave-uniform skip
    const char* Kst = Ks[kt & 1];
    const char* Vst = Vs[kt & 1];

    // ---- S^T = K * Q^T : two 32-key halves, 8 d-chunks each ----
    v16f s0, s1;
#pragma unroll
    for (int r = 0; r < 16; ++r) { s0[r] = 0.f; s1[r] = 0.f; }
    __builtin_amdgcn_s_setprio(1);
#pragma unroll
    for (int c = 0; c < 8; ++c) {
      int cofs = (c * 32 + g * 16);
      v8h kf0 = *(const v8h*)(Kst + l31 * 256 + (cofs ^ ((l31 & 7) << 4)));
      v8h kf1 = *(const v8h*)(Kst + (32 + l31) * 256 + (cofs ^ ((l31 & 7) << 4)));
      s0 = __builtin_amdgcn_mfma_f32_32x32x16_f16(kf0, qf[c], s0, 0, 0, 0);
      s1 = __builtin_amdgcn_mfma_f32_32x32x16_f16(kf1, qf[c], s1, 0, 0, 0);
    }
    __builtin_amdgcn_s_setprio(0);

    // ---- scale + causal mask; pv[i] holds key kv0 + 32*(i>>4) + kofs ----
    const bool diag = (kt == tile);
    const int kv0 = kt * 64;
    float pv[32];
#pragma unroll
    for (int r = 0; r < 16; ++r) {
      int kofs = (r & 3) + 8 * (r >> 2) + 4 * g;
      float a = s0[r] * scale;
      float b = s1[r] * scale;
      if (diag) {
        if (kv0 + kofs > q) a = -1e4f;
        if (kv0 + 32 + kofs > q) b = -1e4f;
      }
      pv[r] = a;
      pv[16 + r] = b;
    }

    // ---- row max: in-lane tree + cross-half merge ----
    float mx[8];
#pragma unroll
    for (int i = 0; i < 8; ++i)
      mx[i] = fmaxf(fmaxf(pv[i], pv[i + 8]), fmaxf(pv[i + 16], pv[i + 24]));
    float pm = fmaxf(fmaxf(fmaxf(mx[0], mx[1]), fmaxf(mx[2], mx[3])),
                     fmaxf(fmaxf(mx[4], mx[5]), fmaxf(mx[6], mx[7])));
    float pmall = fmaxf(pm, __shfl_xor(pm, 32, 64));

    // ---- defer-max (T13, THR=8) ----
    float mnew;
    if (__all(pmall - m_run <= 8.f)) {
      mnew = m_run;
    } else {
      mnew = fmaxf(m_run, pmall);
      float alpha = __expf(m_run - mnew);
      m_run = mnew;
      l_run *= alpha;
#pragma unroll
      for (int dc = 0; dc < 4; ++dc)
#pragma unroll
        for (int r = 0; r < 16; ++r) oT[dc][r] *= alpha;
    }

    // ---- exp + row sum ----
    float sacc0 = 0.f, sacc1 = 0.f, sacc2 = 0.f, sacc3 = 0.f;
#pragma unroll
    for (int i = 0; i < 8; ++i) { pv[i] = __expf(pv[i] - mnew); sacc0 += pv[i]; }
#pragma unroll
    for (int i = 8; i < 16; ++i) { pv[i] = __expf(pv[i] - mnew); sacc1 += pv[i]; }
#pragma unroll
    for (int i = 16; i < 24; ++i) { pv[i] = __expf(pv[i] - mnew); sacc2 += pv[i]; }
#pragma unroll
    for (int i = 24; i < 32; ++i) { pv[i] = __expf(pv[i] - mnew); sacc3 += pv[i]; }
    float ssum = (sacc0 + sacc1) + (sacc2 + sacc3);
    l_run += ssum + __shfl_xor(ssum, 32, 64);

    // ---- O^T += VT * P^T : P-frags via cvt_pk + cross-half exchange ----
    __builtin_amdgcn_s_setprio(1);
#pragma unroll
    for (int c = 0; c < 4; ++c) {          // key chunk of 16
      int base = (c >> 1) * 16 + (c & 1) * 8;
      uint32_t P0 = pkh(pv[base + 0], pv[base + 1]);
      uint32_t P1 = pkh(pv[base + 2], pv[base + 3]);
      uint32_t P2 = pkh(pv[base + 4], pv[base + 5]);
      uint32_t P3 = pkh(pv[base + 6], pv[base + 7]);
      uint32_t T0 = g ? P0 : P2;
      uint32_t T1 = g ? P1 : P3;
      uint32_t U0 = xswap32(T0);
      uint32_t U1 = xswap32(T1);
      union { uint32_t u[4]; v8h h; } pu;
      pu.u[0] = g ? U0 : P0;
      pu.u[1] = g ? U1 : P1;
      pu.u[2] = g ? P2 : U0;
      pu.u[3] = g ? P3 : U1;
      v8h pf = pu.h;
      int cofs = c * 32 + g * 16;
#pragma unroll
      for (int dc = 0; dc < 4; ++dc) {
        int vrow = dc * 32 + l31;
        v8h vf = *(const v8h*)(Vst + vrow * 128 + (cofs ^ ((vrow & 7) << 4)));
        oT[dc] = __builtin_amdgcn_mfma_f32_32x32x16_f16(vf, pf, oT[dc], 0, 0, 0);
      }
    }
    __builtin_amdgcn_s_setprio(0);
  }

  // ---- epilogue: O^T col q per lane; divide by l and store ----
  const float inv = 1.0f / l_run;
  const int b = bh >> 4;
  const int hh = bh & 15;
  _Float16* orow = ctx + ((size_t)q * BATCH + b) * HID + hh * HD;
#pragma unroll
  for (int dc = 0; dc < 4; ++dc) {
#pragma unroll
    for (int rr = 0; rr < 4; ++rr) {
      v2h w0 = pkh2(oT[dc][4 * rr + 0] * inv, oT[dc][4 * rr + 1] * inv);
      v2h w1 = pkh2(oT[dc][4 * rr + 2] * inv, oT[dc][4 * rr + 3] * inv);
      v4h o4; o4[0] = w0[0]; o4[1] = w0[1]; o4[2] = w1[0]; o4[3] = w1[1];
      *(v4h*)(orow + dc * 32 + rr * 8 + g * 4) = o4;
    }
  }
}

// ---------------------------------------------------------------------------

extern "C" void kernel_launch(void* const* d_in, const int* in_sizes, int n_in,
                              void* d_out, int out_size, void* d_ws, size_t ws_size,
                              hipStream_t stream) {
  const float* x = (const float*)d_in[0];
  const float* w_qkv = (const float*)d_in[1];
  const float* w_dense = (const float*)d_in[2];
  float* out = (float*)d_out;
  char* ws = (char*)d_ws;

  _Float16* xb    = (_Float16*)(ws);               // 4096x2048        16 MB
  _Float16* wqkvT = (_Float16*)(ws + 16777216);    // 6144x2048        24 MB
  _Float16* wdT   = (_Float16*)(ws + 41943040);    // 2048x2048         8 MB
  _Float16* Qb    = (_Float16*)(ws + 50331648);    // [32][2048][128]  16 MB
  _Float16* Kb    = (_Float16*)(ws + 67108864);    // [32][2048][128]  16 MB
  _Float16* VTb   = (_Float16*)(ws + 100663296);   // [32][128][2048]  16 MB
  _Float16* ctx   = (_Float16*)(ws + 117440512);   // 4096x2048        16 MB
  float2* csl     = (float2*)(ws + 134217728);     // 2048x64 float2    1 MB

  cast_x_kernel<<<dim3(8192), dim3(256), 0, stream>>>(x, xb, 2097152);
  transpose_cast_kernel<<<dim3(96, 32), dim3(32, 8), 0, stream>>>(w_qkv, wqkvT, 2048, 6144);
  transpose_cast_kernel<<<dim3(32, 32), dim3(32, 8), 0, stream>>>(w_dense, wdT, 2048, 2048);
  rope_table_kernel<<<dim3(2048), dim3(64), 0, stream>>>(csl);

  gemm_kernel<0><<<dim3(1536), dim3(256), 0, stream>>>(xb, wqkvT, 4096, 6144, 2048, 32,
                                                       Qb, Kb, VTb, (float*)nullptr, csl);
  attn_kernel<<<dim3(512), dim3(256), 0, stream>>>(Qb, Kb, VTb, ctx);
  gemm_kernel<1><<<dim3(512), dim3(256), 0, stream>>>(ctx, wdT, 4096, 2048, 2048, 32,
                                                      (_Float16*)nullptr, (_Float16*)nullptr,
                                                      (_Float16*)nullptr, out,
                                                      (const float2*)nullptr);
}